// Round 4
// baseline (358.445 us; speedup 1.0000x reference)
//
#include <hip/hip_runtime.h>
#include <hip/hip_bf16.h>

#define H 1024
#define V 50257
#define L 100
#define NB 512   // persistent grid: 512 blocks x 256 threads (2 blocks/CU guaranteed)

// ---------- helpers ----------

__device__ __forceinline__ float wave_sum(float v) {
    #pragma unroll
    for (int off = 32; off > 0; off >>= 1) v += __shfl_down(v, off, 64);
    return v;
}

// dot of one 1024-element row segment against x, both float4-aligned; lane in [0,64)
__device__ __forceinline__ float dot1024(const float4* w, const float4* x, int lane) {
    float acc = 0.f;
    #pragma unroll
    for (int j = 0; j < 4; j++) {
        float4 a = w[lane + 64 * j];
        float4 b = x[lane + 64 * j];
        acc += a.x * b.x + a.y * b.y + a.z * b.z + a.w * b.w;
    }
    return acc;
}

// grid-wide barrier: one atomic per block, thread-0 spin, agent-scope fences.
// Bounded spin: on (impossible) overrun we fall through -> wrong answer, not a hang.
__device__ __forceinline__ void gbar(unsigned* cnt, int i) {
    __syncthreads();
    if (threadIdx.x == 0) {
        __threadfence();   // release: make this block's writes visible device-wide
        __hip_atomic_fetch_add(&cnt[i], 1u, __ATOMIC_ACQ_REL, __HIP_MEMORY_SCOPE_AGENT);
        for (long k = 0; k < 200000000L; k++) {
            if (__hip_atomic_load(&cnt[i], __ATOMIC_ACQUIRE, __HIP_MEMORY_SCOPE_AGENT)
                >= (unsigned)NB) break;
            __builtin_amdgcn_s_sleep(8);
        }
        __threadfence();   // acquire: invalidate caches before reading others' data
    }
    __syncthreads();
}

// ---------- the whole decoder step as one persistent kernel ----------

__global__ __launch_bounds__(256, 2) void fused_all(
    const int* token, const float* hidden, const float* enc, const float* embedding,
    const float* attn_w, const float* attn_b, const float* comb_w, const float* comb_b,
    const float* w_ih, const float* w_hh, const float* b_ih, const float* b_hh,
    const float* out_w, const float* out_b, float* out, float* ws, unsigned* cnt)
{
    __shared__ float red[8];
    __shared__ float aw_s[128];
    __shared__ float part[4][64];
    __shared__ float sm[4], ss[4];

    int t = threadIdx.x, lane = t & 63, wv = t >> 6;
    int W = blockIdx.x * 4 + wv;          // global wave id, 0..2047

    float* ws_log = ws;                   // 100
    float* ws_app = ws + 128;             // 1024
    float* ws_x   = ws + 1152;            // 1024
    float* ws_gh  = ws + 2176;            // 3072
    float* ws_pm  = ws + 5248;            // 512
    float* ws_ps  = ws + 5760;            // 512
    float* ws_hn  = ws + 6272;            // 1024

    const float4* e4 = (const float4*)(embedding + (size_t)token[0] * H);
    const float4* h4 = (const float4*)hidden;

    // ---- P1: attn logits (waves 0..99) + gh = w_hh @ h0 + b_hh (all waves) ----
    if (W < L) {
        const float4* wr = (const float4*)(attn_w + (size_t)W * (2 * H));
        float acc = dot1024(wr, e4, lane) + dot1024(wr + 256, h4, lane);
        acc = wave_sum(acc);
        if (lane == 0) ws_log[W] = acc + attn_b[W];
    }
    for (int r = W; r < 3 * H; r += 4 * NB) {
        const float4* wr = (const float4*)(w_hh + (size_t)r * H);
        float acc = wave_sum(dot1024(wr, h4, lane));
        if (lane == 0) ws_gh[r] = acc + b_hh[r];
    }
    gbar(cnt, 0);

    // ---- P2: softmax over L + attn_applied (blocks 0..15) ----
    if (blockIdx.x < 16) {
        float x = (t < L) ? ws_log[t] : -1e30f;
        float mv = x;
        #pragma unroll
        for (int off = 32; off > 0; off >>= 1) mv = fmaxf(mv, __shfl_down(mv, off, 64));
        if (lane == 0) red[wv] = mv;
        __syncthreads();
        float m = fmaxf(fmaxf(red[0], red[1]), fmaxf(red[2], red[3]));
        float e = (t < L) ? expf(x - m) : 0.f;
        float sv = wave_sum(e);
        if (lane == 0) red[4 + wv] = sv;
        __syncthreads();
        float s = red[4] + red[5] + red[6] + red[7];
        float aw = e / s;
        if (t < 128) aw_s[t] = aw;                    // zero past L
        if (blockIdx.x == 0 && t < L) out[V + H + t] = aw;
        __syncthreads();
        int h = blockIdx.x * 64 + lane;
        float acc = 0.f;
        #pragma unroll
        for (int i = 0; i < 25; i++) {
            int l = wv * 25 + i;
            acc += aw_s[l] * enc[l * H + h];
        }
        part[wv][lane] = acc;
        __syncthreads();
        if (wv == 0)
            ws_app[h] = part[0][lane] + part[1][lane] + part[2][lane] + part[3][lane];
    }
    gbar(cnt, 1);

    // ---- P3: x = relu(concat(emb, app) @ comb_w.T + comb_b), waves 0..1023 ----
    if (W < H) {
        const float4* a4 = (const float4*)ws_app;
        const float4* wr = (const float4*)(comb_w + (size_t)W * (2 * H));
        float acc = dot1024(wr, e4, lane) + dot1024(wr + 256, a4, lane);
        acc = wave_sum(acc);
        if (lane == 0) ws_x[W] = fmaxf(acc + comb_b[W], 0.0f);
    }
    gbar(cnt, 2);

    // ---- P4: gi = w_ih @ x; gates -> h_new (wave per hidden unit) ----
    if (W < H) {
        const float4* x4 = (const float4*)ws_x;
        float a0 = dot1024((const float4*)(w_ih + (size_t)W * H), x4, lane);
        float a1 = dot1024((const float4*)(w_ih + (size_t)(H + W) * H), x4, lane);
        float a2 = dot1024((const float4*)(w_ih + (size_t)(2 * H + W) * H), x4, lane);
        a0 = wave_sum(a0); a1 = wave_sum(a1); a2 = wave_sum(a2);
        if (lane == 0) {
            float ir = a0 + b_ih[W], iz = a1 + b_ih[H + W], in_ = a2 + b_ih[2 * H + W];
            float hr = ws_gh[W], hz = ws_gh[H + W], hn = ws_gh[2 * H + W];
            float r = 1.f / (1.f + expf(-(ir + hr)));
            float z = 1.f / (1.f + expf(-(iz + hz)));
            float n = tanhf(in_ + r * hn);
            float h0v = hidden[W];
            float v = (1.f - z) * n + z * h0v;
            out[V + W] = v;
            ws_hn[W] = v;
        }
    }
    gbar(cnt, 3);

    // ---- P5: logits = h_new @ out_w.T + out_b, 4 rows/wave/iter, online (m,s) ----
    {
        const float4* hh = (const float4*)ws_hn;
        float4 v0 = hh[lane], v1 = hh[lane + 64], v2 = hh[lane + 128], v3 = hh[lane + 192];
        float m = -1e30f, s = 0.f;
        for (int r0 = W * 4; r0 < V; r0 += NB * 16) {
            float acc[4] = {0.f, 0.f, 0.f, 0.f};
            #pragma unroll
            for (int i = 0; i < 4; i++) {
                int r = r0 + i;
                if (r < V) {
                    const float4* wr = (const float4*)(out_w + (size_t)r * H);
                    float4 a = wr[lane], b = wr[lane + 64], c = wr[lane + 128], d = wr[lane + 192];
                    acc[i] = a.x * v0.x + a.y * v0.y + a.z * v0.z + a.w * v0.w
                           + b.x * v1.x + b.y * v1.y + b.z * v1.z + b.w * v1.w
                           + c.x * v2.x + c.y * v2.y + c.z * v2.z + c.w * v2.w
                           + d.x * v3.x + d.y * v3.y + d.z * v3.z + d.w * v3.w;
                }
            }
            #pragma unroll
            for (int off = 32; off > 0; off >>= 1) {
                #pragma unroll
                for (int i = 0; i < 4; i++) acc[i] += __shfl_down(acc[i], off, 64);
            }
            if (lane == 0) {
                #pragma unroll
                for (int i = 0; i < 4; i++) {
                    int r = r0 + i;
                    if (r < V) {
                        float lg = acc[i] + out_b[r];
                        out[r] = lg;
                        float nm = fmaxf(m, lg);
                        s = s * expf(m - nm) + expf(lg - nm);
                        m = nm;
                    }
                }
            }
        }
        if (lane == 0) { sm[wv] = m; ss[wv] = s; }
        __syncthreads();
        if (t == 0) {
            m = sm[0]; s = ss[0];
            #pragma unroll
            for (int i = 1; i < 4; i++) {
                float nm = fmaxf(m, sm[i]);
                s = s * expf(m - nm) + ss[i] * expf(sm[i] - nm);
                m = nm;
            }
            ws_pm[blockIdx.x] = m;
            ws_ps[blockIdx.x] = s;
        }
    }
    gbar(cnt, 4);

    // ---- P6: redundant 512-pair reduce per block + in-place correction ----
    {
        float m, s;
        {
            float m1 = ws_pm[t],      s1 = ws_ps[t];
            float m2 = ws_pm[t + 256], s2 = ws_ps[t + 256];
            float nm = fmaxf(m1, m2);
            s = s1 * expf(m1 - nm) + s2 * expf(m2 - nm);
            m = nm;
        }
        #pragma unroll
        for (int off = 32; off > 0; off >>= 1) {
            float om = __shfl_down(m, off, 64);
            float os = __shfl_down(s, off, 64);
            float nm = fmaxf(m, om);
            s = s * expf(m - nm) + os * expf(om - nm);
            m = nm;
        }
        if (lane == 0) { sm[wv] = m; ss[wv] = s; }
        __syncthreads();
        if (t == 0) {
            m = sm[0]; s = ss[0];
            #pragma unroll
            for (int i = 1; i < 4; i++) {
                float nm = fmaxf(m, sm[i]);
                s = s * expf(m - nm) + ss[i] * expf(sm[i] - nm);
                m = nm;
            }
            red[0] = m; red[1] = logf(s);
        }
        __syncthreads();
        float corr = red[0] + red[1];
        int idx = blockIdx.x * 256 + t;
        if (idx < V) out[idx] -= corr;
    }
}

// ---------- launch ----------

extern "C" void kernel_launch(void* const* d_in, const int* in_sizes, int n_in,
                              void* d_out, int out_size, void* d_ws, size_t ws_size,
                              hipStream_t stream) {
    const int*   token     = (const int*)d_in[0];
    const float* hidden    = (const float*)d_in[1];
    const float* enc       = (const float*)d_in[2];
    const float* embedding = (const float*)d_in[3];
    const float* attn_w    = (const float*)d_in[4];
    const float* attn_b    = (const float*)d_in[5];
    const float* comb_w    = (const float*)d_in[6];
    const float* comb_b    = (const float*)d_in[7];
    const float* w_ih      = (const float*)d_in[8];
    const float* w_hh      = (const float*)d_in[9];
    const float* b_ih      = (const float*)d_in[10];
    const float* b_hh      = (const float*)d_in[11];
    const float* out_w     = (const float*)d_in[12];
    const float* out_b     = (const float*)d_in[13];

    float* out = (float*)d_out;           // [0,V) log_softmax | [V,V+H) h_new | [V+H,V+H+L) attn_w
    float* ws  = (float*)d_ws;
    unsigned* cnt = (unsigned*)(ws + 7296);   // 5 barrier counters (32B region)

    hipMemsetAsync(cnt, 0, 32, stream);
    fused_all<<<dim3(NB), dim3(256), 0, stream>>>(token, hidden, enc, embedding,
                                                  attn_w, attn_b, comb_w, comb_b,
                                                  w_ih, w_hh, b_ih, b_hh,
                                                  out_w, out_b, out, ws, cnt);
}

// Round 5
// 78.147 us; speedup vs baseline: 4.5868x; 4.5868x over previous
//
#include <hip/hip_runtime.h>
#include <hip/hip_bf16.h>

#define H 1024
#define V 50257
#define L 100
#define NPART 1024   // kD grid size == number of (m,s) partial pairs

// ---------- helpers ----------

__device__ __forceinline__ float wave_sum(float v) {
    #pragma unroll
    for (int off = 32; off > 0; off >>= 1) v += __shfl_down(v, off, 64);
    return v;
}

__device__ __forceinline__ float dot1024(const float4* w, const float4* x, int lane) {
    float acc = 0.f;
    #pragma unroll
    for (int j = 0; j < 4; j++) {
        float4 a = w[lane + 64 * j];
        float4 b = x[lane + 64 * j];
        acc += a.x * b.x + a.y * b.y + a.z * b.z + a.w * b.w;
    }
    return acc;
}

// ---------- kSC: logits (redundant) + softmax + apply (redundant, LDS) + combine ----------
// grid 128 x 256. Block computes everything up to `app`, then its 8 comb_w rows.

__global__ void kSC(const int* token, const float* hidden, const float* embedding,
                    const float* attn_w, const float* attn_b, const float* enc,
                    const float* comb_w, const float* comb_b,
                    float* ws_x, float* out_attnw) {
    __shared__ float lg[L];
    __shared__ float aw[128];
    __shared__ float4 app4[256];
    __shared__ float red[8];
    int t = threadIdx.x, lane = t & 63, wv = t >> 6;

    const float4* e4 = (const float4*)(embedding + (size_t)token[0] * H);
    const float4* h4 = (const float4*)hidden;

    // phase a: all 100 logits, 25 per wave (L2/L3-hot attn_w)
    for (int i = 0; i < 25; i++) {
        int r = wv * 25 + i;
        const float4* wr = (const float4*)(attn_w + (size_t)r * (2 * H));
        float acc = dot1024(wr, e4, lane) + dot1024(wr + 256, h4, lane);
        acc = wave_sum(acc);
        if (lane == 0) lg[r] = acc + attn_b[r];
    }
    __syncthreads();

    // phase b: parallel softmax over 100
    float x = (t < L) ? lg[t] : -1e30f;
    float mv = x;
    #pragma unroll
    for (int off = 32; off > 0; off >>= 1) mv = fmaxf(mv, __shfl_down(mv, off, 64));
    if (lane == 0) red[wv] = mv;
    __syncthreads();
    float m = fmaxf(fmaxf(red[0], red[1]), fmaxf(red[2], red[3]));
    float e = (t < L) ? expf(x - m) : 0.f;
    float sv = wave_sum(e);
    if (lane == 0) red[4 + wv] = sv;
    __syncthreads();
    float s = red[4] + red[5] + red[6] + red[7];
    if (t < 128) aw[t] = e / s;                    // zero-padded past L
    if (blockIdx.x == 0 && t < L) out_attnw[t] = e / s;
    __syncthreads();

    // phase c: app = aw @ enc, redundant per block, coalesced float4
    {
        int c = wv * 64 + lane;                    // float4 column 0..255
        float4 acc4 = make_float4(0.f, 0.f, 0.f, 0.f);
        for (int l = 0; l < L; l++) {
            float a = aw[l];
            float4 ev = ((const float4*)(enc + (size_t)l * H))[c];
            acc4.x += a * ev.x; acc4.y += a * ev.y;
            acc4.z += a * ev.z; acc4.w += a * ev.w;
        }
        app4[c] = acc4;
    }
    __syncthreads();

    // phase d: this block's 8 comb_w rows (2 per wave)
    #pragma unroll
    for (int k = 0; k < 2; k++) {
        int r = (blockIdx.x * 4 + wv) * 2 + k;     // 0..1023
        const float4* wr = (const float4*)(comb_w + (size_t)r * (2 * H));
        float acc = dot1024(wr, e4, lane) + dot1024(wr + 256, app4, lane);
        acc = wave_sum(acc);
        if (lane == 0) ws_x[r] = fmaxf(acc + comb_b[r], 0.0f);
    }
}

// ---------- kGRU: gi + gh + gates, wave per hidden unit ----------

__global__ void kGRU(const float* ws_x, const float* hidden,
                     const float* w_ih, const float* w_hh,
                     const float* b_ih, const float* b_hh,
                     float* out_h, float* ws_hn) {
    int lane = threadIdx.x & 63, wv = threadIdx.x >> 6;
    int h = blockIdx.x * 4 + wv;                  // 0..1023
    const float4* x4 = (const float4*)ws_x;
    const float4* h4 = (const float4*)hidden;
    float acc[6] = {0.f, 0.f, 0.f, 0.f, 0.f, 0.f};
    #pragma unroll
    for (int j = 0; j < 4; j++) {
        float4 xv = x4[lane + 64 * j];
        float4 hv = h4[lane + 64 * j];
        #pragma unroll
        for (int k = 0; k < 3; k++) {
            float4 w = ((const float4*)(w_ih + (size_t)(k * H + h) * H))[lane + 64 * j];
            acc[k] += w.x * xv.x + w.y * xv.y + w.z * xv.z + w.w * xv.w;
        }
        #pragma unroll
        for (int k = 0; k < 3; k++) {
            float4 w = ((const float4*)(w_hh + (size_t)(k * H + h) * H))[lane + 64 * j];
            acc[3 + k] += w.x * hv.x + w.y * hv.y + w.z * hv.z + w.w * hv.w;
        }
    }
    #pragma unroll
    for (int off = 32; off > 0; off >>= 1) {
        #pragma unroll
        for (int k = 0; k < 6; k++) acc[k] += __shfl_down(acc[k], off, 64);
    }
    if (lane == 0) {
        float ir = acc[0] + b_ih[h], iz = acc[1] + b_ih[H + h], in_ = acc[2] + b_ih[2 * H + h];
        float hr = acc[3] + b_hh[h], hz = acc[4] + b_hh[H + h], hn = acc[5] + b_hh[2 * H + h];
        float r = 1.f / (1.f + expf(-(ir + hr)));
        float z = 1.f / (1.f + expf(-(iz + hz)));
        float n = tanhf(in_ + r * hn);
        float h0 = hidden[h];
        float v = (1.f - z) * n + z * h0;
        out_h[h] = v;
        ws_hn[h] = v;
    }
}

// ---------- kD: logits = h_new @ out_w.T + out_b, 4 rows/wave/iter + online (m,s) ----------

__global__ void kD_outproj(const float* hn, const float* out_w, const float* out_b,
                           float* out_logits, float* ws_pm, float* ws_ps) {
    __shared__ float sm[4], ss[4];
    int lane = threadIdx.x & 63;
    int wv   = threadIdx.x >> 6;
    const float4* h4 = (const float4*)hn;
    float4 h0 = h4[lane], h1 = h4[lane + 64], h2 = h4[lane + 128], h3 = h4[lane + 192];
    float m = -1e30f, s = 0.f;
    int wid = blockIdx.x * 4 + wv;                // 0..4095
    for (int r0 = wid * 4; r0 < V; r0 += NPART * 16) {
        float acc[4] = {0.f, 0.f, 0.f, 0.f};
        #pragma unroll
        for (int i = 0; i < 4; i++) {
            int r = r0 + i;
            if (r < V) {
                const float4* wr = (const float4*)(out_w + (size_t)r * H);
                float4 a = wr[lane], b = wr[lane + 64], c = wr[lane + 128], d = wr[lane + 192];
                acc[i] = a.x * h0.x + a.y * h0.y + a.z * h0.z + a.w * h0.w
                       + b.x * h1.x + b.y * h1.y + b.z * h1.z + b.w * h1.w
                       + c.x * h2.x + c.y * h2.y + c.z * h2.z + c.w * h2.w
                       + d.x * h3.x + d.y * h3.y + d.z * h3.z + d.w * h3.w;
            }
        }
        #pragma unroll
        for (int off = 32; off > 0; off >>= 1) {
            #pragma unroll
            for (int i = 0; i < 4; i++) acc[i] += __shfl_down(acc[i], off, 64);
        }
        if (lane == 0) {
            #pragma unroll
            for (int i = 0; i < 4; i++) {
                int r = r0 + i;
                if (r < V) {
                    float lg = acc[i] + out_b[r];
                    out_logits[r] = lg;
                    float nm = fmaxf(m, lg);
                    s = s * expf(m - nm) + expf(lg - nm);
                    m = nm;
                }
            }
        }
    }
    if (lane == 0) { sm[wv] = m; ss[wv] = s; }
    __syncthreads();
    if (threadIdx.x == 0) {
        m = sm[0]; s = ss[0];
        #pragma unroll
        for (int i = 1; i < 4; i++) {
            float nm = fmaxf(m, sm[i]);
            s = s * expf(m - nm) + ss[i] * expf(sm[i] - nm);
            m = nm;
        }
        ws_pm[blockIdx.x] = m;
        ws_ps[blockIdx.x] = s;
    }
}

// ---------- kE: reduce partials (redundant per block) + in-place log_softmax ----------

__global__ void kE_finalize(const float* ws_pm, const float* ws_ps, float* out) {
    __shared__ float sm[4], ss[4], fm, fs;
    int t = threadIdx.x;
    float m = -1e30f, s = 0.f;
    for (int i = t; i < NPART; i += 256) {
        float pm = ws_pm[i], ps = ws_ps[i];
        float nm = fmaxf(m, pm);
        s = s * expf(m - nm) + ps * expf(pm - nm);
        m = nm;
    }
    #pragma unroll
    for (int off = 32; off > 0; off >>= 1) {
        float om = __shfl_down(m, off, 64);
        float os = __shfl_down(s, off, 64);
        float nm = fmaxf(m, om);
        s = s * expf(m - nm) + os * expf(om - nm);
        m = nm;
    }
    int lane = t & 63, wv = t >> 6;
    if (lane == 0) { sm[wv] = m; ss[wv] = s; }
    __syncthreads();
    if (t == 0) {
        m = sm[0]; s = ss[0];
        #pragma unroll
        for (int i = 1; i < 4; i++) {
            float nm = fmaxf(m, sm[i]);
            s = s * expf(m - nm) + ss[i] * expf(sm[i] - nm);
            m = nm;
        }
        fm = m; fs = logf(s);
    }
    __syncthreads();
    float M = fm, LS = fs;
    for (int v = blockIdx.x * 256 + t; v < V; v += gridDim.x * 256)
        out[v] = out[v] - M - LS;
}

// ---------- launch ----------

extern "C" void kernel_launch(void* const* d_in, const int* in_sizes, int n_in,
                              void* d_out, int out_size, void* d_ws, size_t ws_size,
                              hipStream_t stream) {
    const int*   token     = (const int*)d_in[0];
    const float* hidden    = (const float*)d_in[1];
    const float* enc       = (const float*)d_in[2];
    const float* embedding = (const float*)d_in[3];
    const float* attn_w    = (const float*)d_in[4];
    const float* attn_b    = (const float*)d_in[5];
    const float* comb_w    = (const float*)d_in[6];
    const float* comb_b    = (const float*)d_in[7];
    const float* w_ih      = (const float*)d_in[8];
    const float* w_hh      = (const float*)d_in[9];
    const float* b_ih      = (const float*)d_in[10];
    const float* b_hh      = (const float*)d_in[11];
    const float* out_w     = (const float*)d_in[12];
    const float* out_b     = (const float*)d_in[13];

    float* out = (float*)d_out;           // [0,V) log_softmax | [V,V+H) h_new | [V+H,V+H+L) attn_w
    float* ws  = (float*)d_ws;
    float* ws_x   = ws;                   // 1024
    float* ws_pm  = ws + 1024;            // 1024
    float* ws_ps  = ws + 2048;            // 1024
    float* ws_hn  = ws + 3072;            // 1024

    kSC<<<dim3(128), dim3(256), 0, stream>>>(token, hidden, embedding, attn_w, attn_b,
                                             enc, comb_w, comb_b, ws_x, out + V + H);
    kGRU<<<dim3(256), dim3(256), 0, stream>>>(ws_x, hidden, w_ih, w_hh, b_ih, b_hh,
                                              out + V, ws_hn);
    kD_outproj<<<dim3(NPART), dim3(256), 0, stream>>>(ws_hn, out_w, out_b, out, ws_pm, ws_ps);
    kE_finalize<<<dim3(128), dim3(256), 0, stream>>>(ws_pm, ws_ps, out);
}

// Round 6
// 58.432 us; speedup vs baseline: 6.1343x; 1.3374x over previous
//
#include <hip/hip_runtime.h>
#include <hip/hip_bf16.h>

#define H 1024
#define V 50257
#define L 100
#define NDB 2048   // kD grid: 2048 blocks x 4 waves = 8192 waves (32 waves/CU)

// ---------- helpers ----------

__device__ __forceinline__ float wave_sum(float v) {
    #pragma unroll
    for (int off = 32; off > 0; off >>= 1) v += __shfl_down(v, off, 64);
    return v;
}

__device__ __forceinline__ float dot1024(const float4* w, const float4* x, int lane) {
    float acc = 0.f;
    #pragma unroll
    for (int j = 0; j < 4; j++) {
        float4 a = w[lane + 64 * j];
        float4 b = x[lane + 64 * j];
        acc += a.x * b.x + a.y * b.y + a.z * b.z + a.w * b.w;
    }
    return acc;
}

// ---------- kA: attn logits (wave per row, 100 blocks x 64 threads) ----------

__global__ void kA_logits(const int* token, const float* hidden, const float* embedding,
                          const float* attn_w, const float* attn_b, float* ws_log) {
    int lane = threadIdx.x;                       // block == 1 wave
    int r = blockIdx.x;
    const float4* e4 = (const float4*)(embedding + (size_t)token[0] * H);
    const float4* h4 = (const float4*)hidden;
    const float4* wr = (const float4*)(attn_w + (size_t)r * (2 * H));
    float acc = dot1024(wr, e4, lane) + dot1024(wr + 256, h4, lane);
    acc = wave_sum(acc);
    if (lane == 0) ws_log[r] = acc + attn_b[r];
}

// ---------- kS: parallel softmax + l-parallel attn_applied ----------
// grid 16 x 256. Block b owns h-columns [b*64, b*64+64). Wave w covers l in [w*25, w*25+25).

__global__ void kS_softmax_apply(const float* ws_log, const float* enc,
                                 float* ws_app, float* out_attnw) {
    __shared__ float red[8];
    __shared__ float aw_s[128];
    __shared__ float part[4][64];
    int t = threadIdx.x, lane = t & 63, wv = t >> 6;

    float x = (t < L) ? ws_log[t] : -1e30f;
    float mv = x;
    #pragma unroll
    for (int off = 32; off > 0; off >>= 1) mv = fmaxf(mv, __shfl_down(mv, off, 64));
    if (lane == 0) red[wv] = mv;
    __syncthreads();
    float m = fmaxf(fmaxf(red[0], red[1]), fmaxf(red[2], red[3]));
    float e = (t < L) ? expf(x - m) : 0.f;
    float sv = wave_sum(e);
    if (lane == 0) red[4 + wv] = sv;
    __syncthreads();
    float s = red[4] + red[5] + red[6] + red[7];
    float aw = e / s;
    if (t < 128) aw_s[t] = aw;                    // zero-padded past L
    if (blockIdx.x == 0 && t < L) out_attnw[t] = aw;
    __syncthreads();

    int h = blockIdx.x * 64 + lane;
    float acc = 0.f;
    #pragma unroll
    for (int i = 0; i < 25; i++) {
        int l = wv * 25 + i;
        acc += aw_s[l] * enc[l * H + h];
    }
    part[wv][lane] = acc;
    __syncthreads();
    if (wv == 0)
        ws_app[h] = part[0][lane] + part[1][lane] + part[2][lane] + part[3][lane];
}

// ---------- kComb: x = relu(concat(emb, applied) @ comb_w.T + comb_b), wave per row ----------

__global__ void kComb(const int* token, const float* embedding, const float* ws_app,
                      const float* comb_w, const float* comb_b, float* ws_x) {
    int lane = threadIdx.x & 63, wv = threadIdx.x >> 6;
    int r = blockIdx.x * 4 + wv;                  // grid 256 -> 1024 rows
    const float4* e4 = (const float4*)(embedding + (size_t)token[0] * H);
    const float4* a4 = (const float4*)ws_app;
    const float4* wr = (const float4*)(comb_w + (size_t)r * (2 * H));
    float acc = dot1024(wr, e4, lane) + dot1024(wr + 256, a4, lane);
    acc = wave_sum(acc);
    if (lane == 0) ws_x[r] = fmaxf(acc + comb_b[r], 0.0f);
}

// ---------- kGRU: paired waves — even wave gi triple, odd wave gh triple ----------
// grid 512 x 256: 2048 waves -> 1024 hidden units, 2 waves each.

__global__ void kGRU(const float* ws_x, const float* hidden,
                     const float* w_ih, const float* w_hh,
                     const float* b_ih, const float* b_hh,
                     float* out_h, float* ws_hn) {
    __shared__ float sh[2][2][3];                 // [pair][isGh][gate]
    int lane = threadIdx.x & 63, wv = threadIdx.x >> 6;
    int pair = wv >> 1, isGh = wv & 1;
    int h = blockIdx.x * 2 + pair;                // 0..1023
    const float4* vec = isGh ? (const float4*)hidden : (const float4*)ws_x;
    const float*  Wm  = isGh ? w_hh : w_ih;
    float a0 = dot1024((const float4*)(Wm + (size_t)h * H), vec, lane);
    float a1 = dot1024((const float4*)(Wm + (size_t)(H + h) * H), vec, lane);
    float a2 = dot1024((const float4*)(Wm + (size_t)(2 * H + h) * H), vec, lane);
    a0 = wave_sum(a0); a1 = wave_sum(a1); a2 = wave_sum(a2);
    if (lane == 0) { sh[pair][isGh][0] = a0; sh[pair][isGh][1] = a1; sh[pair][isGh][2] = a2; }
    __syncthreads();
    if (!isGh && lane == 0) {
        float ir = sh[pair][0][0] + b_ih[h], iz = sh[pair][0][1] + b_ih[H + h],
              in_ = sh[pair][0][2] + b_ih[2 * H + h];
        float hr = sh[pair][1][0] + b_hh[h], hz = sh[pair][1][1] + b_hh[H + h],
              hn = sh[pair][1][2] + b_hh[2 * H + h];
        float r = 1.f / (1.f + expf(-(ir + hr)));
        float z = 1.f / (1.f + expf(-(iz + hz)));
        float n = tanhf(in_ + r * hn);
        float h0 = hidden[h];
        float v = (1.f - z) * n + z * h0;
        out_h[h] = v;
        ws_hn[h] = v;
    }
}

// ---------- kD: logits = h_new @ out_w.T + out_b, 2 rows/wave/iter, 8192 waves ----------

__global__ void kD_outproj(const float* hn, const float* out_w, const float* out_b,
                           float* out_logits, float* ws_pm, float* ws_ps) {
    __shared__ float sm[4], ss[4];
    int lane = threadIdx.x & 63;
    int wv   = threadIdx.x >> 6;
    const float4* h4 = (const float4*)hn;
    float4 h0 = h4[lane], h1 = h4[lane + 64], h2 = h4[lane + 128], h3 = h4[lane + 192];
    float m = -1e30f, s = 0.f;
    int wid = blockIdx.x * 4 + wv;                // 0..8191
    for (int r0 = wid * 2; r0 < V; r0 += NDB * 8) {
        float acc[2] = {0.f, 0.f};
        #pragma unroll
        for (int i = 0; i < 2; i++) {
            int r = r0 + i;
            if (r < V) {
                const float4* wr = (const float4*)(out_w + (size_t)r * H);
                float4 a = wr[lane], b = wr[lane + 64], c = wr[lane + 128], d = wr[lane + 192];
                acc[i] = a.x * h0.x + a.y * h0.y + a.z * h0.z + a.w * h0.w
                       + b.x * h1.x + b.y * h1.y + b.z * h1.z + b.w * h1.w
                       + c.x * h2.x + c.y * h2.y + c.z * h2.z + c.w * h2.w
                       + d.x * h3.x + d.y * h3.y + d.z * h3.z + d.w * h3.w;
            }
        }
        #pragma unroll
        for (int off = 32; off > 0; off >>= 1) {
            acc[0] += __shfl_down(acc[0], off, 64);
            acc[1] += __shfl_down(acc[1], off, 64);
        }
        if (lane == 0) {
            #pragma unroll
            for (int i = 0; i < 2; i++) {
                int r = r0 + i;
                if (r < V) {
                    float lg = acc[i] + out_b[r];
                    out_logits[r] = lg;
                    float nm = fmaxf(m, lg);
                    s = s * expf(m - nm) + expf(lg - nm);
                    m = nm;
                }
            }
        }
    }
    if (lane == 0) { sm[wv] = m; ss[wv] = s; }
    __syncthreads();
    if (threadIdx.x == 0) {
        m = sm[0]; s = ss[0];
        #pragma unroll
        for (int i = 1; i < 4; i++) {
            float nm = fmaxf(m, sm[i]);
            s = s * expf(m - nm) + ss[i] * expf(sm[i] - nm);
            m = nm;
        }
        ws_pm[blockIdx.x] = m;
        ws_ps[blockIdx.x] = s;
    }
}

// ---------- kE: reduce 2048 partials (redundant per block) + in-place log_softmax ----------

__global__ void kE_finalize(const float* ws_pm, const float* ws_ps, float* out) {
    __shared__ float sm[4], ss[4], fm, fs;
    int t = threadIdx.x;
    float m = -1e30f, s = 0.f;
    for (int i = t; i < NDB; i += 256) {
        float pm = ws_pm[i], ps = ws_ps[i];
        float nm = fmaxf(m, pm);
        s = s * expf(m - nm) + ps * expf(pm - nm);
        m = nm;
    }
    #pragma unroll
    for (int off = 32; off > 0; off >>= 1) {
        float om = __shfl_down(m, off, 64);
        float os = __shfl_down(s, off, 64);
        float nm = fmaxf(m, om);
        s = s * expf(m - nm) + os * expf(om - nm);
        m = nm;
    }
    int lane = t & 63, wv = t >> 6;
    if (lane == 0) { sm[wv] = m; ss[wv] = s; }
    __syncthreads();
    if (t == 0) {
        m = sm[0]; s = ss[0];
        #pragma unroll
        for (int i = 1; i < 4; i++) {
            float nm = fmaxf(m, sm[i]);
            s = s * expf(m - nm) + ss[i] * expf(sm[i] - nm);
            m = nm;
        }
        fm = m; fs = logf(s);
    }
    __syncthreads();
    float M = fm, LS = fs;
    for (int v = blockIdx.x * 256 + t; v < V; v += gridDim.x * 256)
        out[v] = out[v] - M - LS;
}

// ---------- launch ----------

extern "C" void kernel_launch(void* const* d_in, const int* in_sizes, int n_in,
                              void* d_out, int out_size, void* d_ws, size_t ws_size,
                              hipStream_t stream) {
    const int*   token     = (const int*)d_in[0];
    const float* hidden    = (const float*)d_in[1];
    const float* enc       = (const float*)d_in[2];
    const float* embedding = (const float*)d_in[3];
    const float* attn_w    = (const float*)d_in[4];
    const float* attn_b    = (const float*)d_in[5];
    const float* comb_w    = (const float*)d_in[6];
    const float* comb_b    = (const float*)d_in[7];
    const float* w_ih      = (const float*)d_in[8];
    const float* w_hh      = (const float*)d_in[9];
    const float* b_ih      = (const float*)d_in[10];
    const float* b_hh      = (const float*)d_in[11];
    const float* out_w     = (const float*)d_in[12];
    const float* out_b     = (const float*)d_in[13];

    float* out = (float*)d_out;           // [0,V) log_softmax | [V,V+H) h_new | [V+H,V+H+L) attn_w
    float* ws  = (float*)d_ws;
    float* ws_log = ws;                   // 100
    float* ws_app = ws + 128;             // 1024
    float* ws_x   = ws + 1152;            // 1024
    float* ws_pm  = ws + 2176;            // 2048
    float* ws_ps  = ws + 4224;            // 2048
    float* ws_hn  = ws + 6272;            // 1024

    kA_logits<<<dim3(L), dim3(64), 0, stream>>>(token, hidden, embedding,
                                                attn_w, attn_b, ws_log);
    kS_softmax_apply<<<dim3(16), dim3(256), 0, stream>>>(ws_log, enc, ws_app, out + V + H);
    kComb<<<dim3(256), dim3(256), 0, stream>>>(token, embedding, ws_app,
                                               comb_w, comb_b, ws_x);
    kGRU<<<dim3(512), dim3(256), 0, stream>>>(ws_x, hidden, w_ih, w_hh, b_ih, b_hh,
                                              out + V, ws_hn);
    kD_outproj<<<dim3(NDB), dim3(256), 0, stream>>>(ws_hn, out_w, out_b, out, ws_pm, ws_ps);
    kE_finalize<<<dim3(128), dim3(256), 0, stream>>>(ws_pm, ws_ps, out);
}